// Round 1
// baseline (134.735 us; speedup 1.0000x reference)
//
#include <hip/hip_runtime.h>

// RippleNetPlus fused kernel — 1 block per batch element.
// DIM=32, N_HOP=2, N_MEMORY=32, BATCH=2048.
//
// Structure per block (256 threads = 4 waves = 8 half-wave "groups"):
//   - group g (32 lanes, lane index o = dim) owns memories {4g..4g+3}
//   - fold:  Rh*vs@W1a^T + Rh*M@W1b^T  ==  Rh @ C'  with
//            C'[i][o] = vs_i*W1[o,i] + M_i*W1[o,32+i]   (per hop, amortized
//            over all 32 memories; halves inner-loop VALU)
//   - hidden[o] per memory: sum_i Rh_i*C'[i][o] + |Rh_i-vs_i|*Wc[i][o]
//                                              + |Rh_i-M_i|*Wd[i][o]
//   - Z score via w2-weighted tanh + 32-lane shfl reduce; block softmax;
//     o-vector partials per group; GRU on 192 threads; epilogue on 32.

#define NHOP 2
#define NMEM 32

__device__ __forceinline__ float sigmoid_f(float x){ return 1.0f/(1.0f+__expf(-x)); }
__device__ __forceinline__ float tanh_f(float x){
  float e = __expf(2.0f*x);
  return 1.0f - 2.0f/(e + 1.0f);
}

__global__ __launch_bounds__(256) void ripple_fused(
    const int* __restrict__ h_i, const int* __restrict__ R_i, const int* __restrict__ t_i,
    const int* __restrict__ v_i,
    const float* __restrict__ entity_emb, const float* __restrict__ relation_emb,
    const float* __restrict__ agg_w1, const float* __restrict__ agg_b1,
    const float* __restrict__ agg_w2, const float* __restrict__ agg_b2,
    const float* __restrict__ gru_w_ih, const float* __restrict__ gru_w_hh,
    const float* __restrict__ gru_b_ih, const float* __restrict__ gru_b_hh,
    const float* __restrict__ ans_w, const float* __restrict__ ans_b,
    float* __restrict__ out)
{
  // [i][o][2] = (W1[o,64+i], W1[o,96+i])          8 KB  (static)
  __shared__ __align__(16) float s_wcd[32*32*2];
  // [i][o] = vs_i*W1[o,i] + M_i*W1[o,32+i]        4 KB  (per hop)
  __shared__ __align__(16) float s_cp [32*32];
  // [g][i][mem0..3] packed float4                 4 KB
  __shared__ __align__(16) float s_rh [8*32*4];
  // [i][2] = (vs_i, M_i)
  __shared__ __align__(16) float s_vsM[32*2];
  __shared__ __align__(16) float s_Z[32];
  __shared__ __align__(16) float s_g[32];
  __shared__ __align__(16) float s_opart[8*32];
  __shared__ __align__(16) float s_o[32];
  __shared__ __align__(16) float s_M[32];
  __shared__ __align__(16) float s_gig[192];   // gi[0:96], gh[96:192]

  const int b   = blockIdx.x;
  const int tid = threadIdx.x;
  const int g   = tid >> 5;   // half-wave group 0..7
  const int o   = tid & 31;   // dim / output index

  // ---- one-time: stage Wc/Wd (abs-term columns of W1), packed [i][o] ----
  #pragma unroll
  for (int k = 0; k < 4; ++k){
    int idx = tid + k*256;        // idx == ii*32 + oo
    int ii = idx >> 5, oo = idx & 31;
    s_wcd[idx*2+0] = agg_w1[oo*128 + 64 + ii];
    s_wcd[idx*2+1] = agg_w1[oo*128 + 96 + ii];
  }
  if (tid < 32){
    float v = entity_emb[(size_t)v_i[b]*32 + tid];
    s_vsM[tid*2+0] = v;   // vs
    s_vsM[tid*2+1] = v;   // M starts as vs
    s_M[tid] = v;
  }
  __syncthreads();

  const float b1v = agg_b1[o];
  const float w2v = agg_w2[o];
  const float b2v = agg_b2[0];

  for (int hop = 0; hop < NHOP; ++hop){
    // ---- C' for this hop: [i][o] ----
    #pragma unroll
    for (int k = 0; k < 4; ++k){
      int idx = tid + k*256;
      int ii = idx >> 5, oo = idx & 31;
      s_cp[idx] = s_vsM[ii*2+0]*agg_w1[oo*128 + ii]
                + s_vsM[ii*2+1]*agg_w1[oo*128 + 32 + ii];
    }

    const int ibase = (b*NHOP + hop)*NMEM;

    // ---- Rh for this group's 4 memories (lane = dim) ----
    float rh4[4];
    #pragma unroll
    for (int ml = 0; ml < 4; ++ml){
      int m    = g*4 + ml;
      int ridx = R_i[ibase + m];
      int hidx = h_i[ibase + m];
      const float4* Rrow = (const float4*)(relation_emb + (size_t)ridx*1024 + o*32);
      const float4* hv   = (const float4*)(entity_emb  + (size_t)hidx*32);
      float acc = 0.f;
      #pragma unroll
      for (int jq = 0; jq < 8; ++jq){
        float4 r = Rrow[jq], h = hv[jq];
        acc += r.x*h.x + r.y*h.y + r.z*h.z + r.w*h.w;
      }
      rh4[ml] = acc;
    }
    *(float4*)&s_rh[(g*32 + o)*4] = make_float4(rh4[0], rh4[1], rh4[2], rh4[3]);
    __syncthreads();

    // ---- hidden i-loop: 4 memories per group simultaneously ----
    float acc0 = 0.f, acc1 = 0.f, acc2 = 0.f, acc3 = 0.f;
    #pragma unroll 8
    for (int i = 0; i < 32; ++i){
      float2 vm  = *(const float2*)&s_vsM[i*2];            // broadcast
      float4 rh  = *(const float4*)&s_rh[(g*32 + i)*4];    // group broadcast
      float  cp  = s_cp[i*32 + o];                         // lane-varying
      float2 wcd = *(const float2*)&s_wcd[(i*32 + o)*2];   // lane-varying
      acc0 += rh.x*cp + fabsf(rh.x - vm.x)*wcd.x + fabsf(rh.x - vm.y)*wcd.y;
      acc1 += rh.y*cp + fabsf(rh.y - vm.x)*wcd.x + fabsf(rh.y - vm.y)*wcd.y;
      acc2 += rh.z*cp + fabsf(rh.z - vm.x)*wcd.x + fabsf(rh.z - vm.y)*wcd.y;
      acc3 += rh.w*cp + fabsf(rh.w - vm.x)*wcd.x + fabsf(rh.w - vm.y)*wcd.y;
    }

    // ---- per-memory score Z = w2 . tanh(hidden + b1) + b2 ----
    float accs[4] = {acc0, acc1, acc2, acc3};
    #pragma unroll
    for (int ml = 0; ml < 4; ++ml){
      float sc = tanh_f(accs[ml] + b1v) * w2v;
      #pragma unroll
      for (int s = 16; s > 0; s >>= 1) sc += __shfl_xor(sc, s);
      if (o == 0) s_Z[g*4 + ml] = sc + b2v;
    }
    __syncthreads();

    // ---- softmax over the 32 memories (group 0 only; lanes 0..31 active) ----
    if (tid < 32){
      float z  = s_Z[tid];
      float mx = z;
      #pragma unroll
      for (int s = 16; s > 0; s >>= 1) mx = fmaxf(mx, __shfl_xor(mx, s));
      float e  = __expf(z - mx);
      float sm = e;
      #pragma unroll
      for (int s = 16; s > 0; s >>= 1) sm += __shfl_xor(sm, s);
      s_g[tid] = e / sm;
    }
    __syncthreads();

    // ---- o = sum_m g[m] * t_m  (partials per group, then reduce) ----
    float po = 0.f;
    #pragma unroll
    for (int ml = 0; ml < 4; ++ml){
      int m    = g*4 + ml;
      int tidx = t_i[ibase + m];
      po += s_g[m] * entity_emb[(size_t)tidx*32 + o];
    }
    s_opart[g*32 + o] = po;
    __syncthreads();
    if (tid < 32){
      float ov = 0.f;
      #pragma unroll
      for (int gg = 0; gg < 8; ++gg) ov += s_opart[gg*32 + tid];
      s_o[tid] = ov;
    }
    __syncthreads();

    // ---- GRU gates: gi on threads 0..95, gh on threads 128..223 ----
    if (tid < 96){
      const float* w = gru_w_ih + ((size_t)hop*96 + tid)*32;
      float a = gru_b_ih[hop*96 + tid];
      const float4* xo = (const float4*)s_o;
      #pragma unroll
      for (int jq = 0; jq < 8; ++jq){
        float4 wv = ((const float4*)w)[jq]; float4 xv = xo[jq];
        a += wv.x*xv.x + wv.y*xv.y + wv.z*xv.z + wv.w*xv.w;
      }
      s_gig[tid] = a;
    } else if (tid >= 128 && tid < 224){
      int t = tid - 128;
      const float* w = gru_w_hh + ((size_t)hop*96 + t)*32;
      float a = gru_b_hh[hop*96 + t];
      const float4* xm = (const float4*)s_M;
      #pragma unroll
      for (int jq = 0; jq < 8; ++jq){
        float4 wv = ((const float4*)w)[jq]; float4 xv = xm[jq];
        a += wv.x*xv.x + wv.y*xv.y + wv.z*xv.z + wv.w*xv.w;
      }
      s_gig[96 + t] = a;
    }
    __syncthreads();

    // ---- GRU state update (lanes 0..31) ----
    if (tid < 32){
      float ir = s_gig[tid],      iz = s_gig[32 + tid],  in_ = s_gig[64 + tid];
      float hr = s_gig[96 + tid], hz = s_gig[128 + tid], hn  = s_gig[160 + tid];
      float r  = sigmoid_f(ir + hr);
      float zz = sigmoid_f(iz + hz);
      float n  = tanh_f(in_ + r*hn);
      float Mn = (1.f - zz)*n + zz*s_M[tid];
      s_M[tid] = Mn;
      s_vsM[tid*2+1] = Mn;
    }
    __syncthreads();
  }

  // ---- epilogue: out[b] = sum_o vs_o * sigmoid(M @ ans_w.T + ans_b)_o ----
  if (tid < 32){
    const float* w = ans_w + tid*32;
    float a = ans_b[tid];
    #pragma unroll
    for (int jq = 0; jq < 8; ++jq){
      float4 wv = ((const float4*)w)[jq]; float4 mv = ((const float4*)s_M)[jq];
      a += wv.x*mv.x + wv.y*mv.y + wv.z*mv.z + wv.w*mv.w;
    }
    float mw  = sigmoid_f(a);
    float val = s_vsM[tid*2+0]*mw;
    #pragma unroll
    for (int s = 16; s > 0; s >>= 1) val += __shfl_xor(val, s);
    if (tid == 0) out[b] = val;
  }
}

extern "C" void kernel_launch(void* const* d_in, const int* in_sizes, int n_in,
                              void* d_out, int out_size, void* d_ws, size_t ws_size,
                              hipStream_t stream) {
  const int*   h_i          = (const int*)  d_in[0];
  const int*   R_i          = (const int*)  d_in[1];
  const int*   t_i          = (const int*)  d_in[2];
  const int*   v_i          = (const int*)  d_in[3];
  const float* entity_emb   = (const float*)d_in[4];
  const float* relation_emb = (const float*)d_in[5];
  const float* agg_w1       = (const float*)d_in[6];
  const float* agg_b1       = (const float*)d_in[7];
  const float* agg_w2       = (const float*)d_in[8];
  const float* agg_b2       = (const float*)d_in[9];
  const float* gru_w_ih     = (const float*)d_in[10];
  const float* gru_w_hh     = (const float*)d_in[11];
  const float* gru_b_ih     = (const float*)d_in[12];
  const float* gru_b_hh     = (const float*)d_in[13];
  const float* ans_w        = (const float*)d_in[14];
  const float* ans_b        = (const float*)d_in[15];
  float* outp = (float*)d_out;

  const int batch = in_sizes[3];   // v_i element count
  ripple_fused<<<batch, 256, 0, stream>>>(
      h_i, R_i, t_i, v_i, entity_emb, relation_emb,
      agg_w1, agg_b1, agg_w2, agg_b2,
      gru_w_ih, gru_w_hh, gru_b_ih, gru_b_hh,
      ans_w, ans_b, outp);
}

// Round 2
// 71.840 us; speedup vs baseline: 1.8755x; 1.8755x over previous
//
#include <hip/hip_runtime.h>

// RippleNetPlus fused kernel — 1 block per batch element.
// DIM=32, N_HOP=2, N_MEMORY=32, BATCH=2048.
//
// Round 2: coalesced Rh loads. Each group's 32 lanes cooperatively load a
// memory's 32x32 relation matrix as 8 contiguous 512B b128 loads (8 cache
// lines per wave-instruction instead of 64 with the per-lane-row pattern),
// then a packed 3-stage butterfly over 8-lane clusters reduces the partial
// dots so lane c*4+r holds Rh[row]. Also: t-rows prefetched into registers
// at hop start (independent of softmax) to hide gather latency.

#define NHOP 2
#define NMEM 32

__device__ __forceinline__ float sigmoid_f(float x){ return 1.0f/(1.0f+__expf(-x)); }
__device__ __forceinline__ float tanh_f(float x){
  float e = __expf(2.0f*x);
  return 1.0f - 2.0f/(e + 1.0f);
}

__global__ __launch_bounds__(256) void ripple_fused(
    const int* __restrict__ h_i, const int* __restrict__ R_i, const int* __restrict__ t_i,
    const int* __restrict__ v_i,
    const float* __restrict__ entity_emb, const float* __restrict__ relation_emb,
    const float* __restrict__ agg_w1, const float* __restrict__ agg_b1,
    const float* __restrict__ agg_w2, const float* __restrict__ agg_b2,
    const float* __restrict__ gru_w_ih, const float* __restrict__ gru_w_hh,
    const float* __restrict__ gru_b_ih, const float* __restrict__ gru_b_hh,
    const float* __restrict__ ans_w, const float* __restrict__ ans_b,
    float* __restrict__ out)
{
  // [i][o][2] = (W1[o,64+i], W1[o,96+i])          8 KB  (static)
  __shared__ __align__(16) float s_wcd[32*32*2];
  // [i][o] = vs_i*W1[o,i] + M_i*W1[o,32+i]        4 KB  (per hop)
  __shared__ __align__(16) float s_cp [32*32];
  // [g][i][mem0..3] packed float4                 4 KB
  __shared__ __align__(16) float s_rh [8*32*4];
  // [i][2] = (vs_i, M_i)
  __shared__ __align__(16) float s_vsM[32*2];
  __shared__ __align__(16) float s_Z[32];
  __shared__ __align__(16) float s_g[32];
  __shared__ __align__(16) float s_opart[8*32];
  __shared__ __align__(16) float s_o[32];
  __shared__ __align__(16) float s_M[32];
  __shared__ __align__(16) float s_gig[192];   // gi[0:96], gh[96:192]

  const int b   = blockIdx.x;
  const int tid = threadIdx.x;
  const int g   = tid >> 5;   // half-wave group 0..7
  const int o   = tid & 31;   // dim / output index
  const int c   = o & 7;      // 8-lane cluster index
  const int r_  = o >> 3;     // row-within-quad 0..3

  // ---- one-time: stage Wc/Wd (abs-term columns of W1), packed [i][o] ----
  #pragma unroll
  for (int k = 0; k < 4; ++k){
    int idx = tid + k*256;        // idx == ii*32 + oo
    int ii = idx >> 5, oo = idx & 31;
    s_wcd[idx*2+0] = agg_w1[oo*128 + 64 + ii];
    s_wcd[idx*2+1] = agg_w1[oo*128 + 96 + ii];
  }
  if (tid < 32){
    float v = entity_emb[(size_t)v_i[b]*32 + tid];
    s_vsM[tid*2+0] = v;   // vs
    s_vsM[tid*2+1] = v;   // M starts as vs
    s_M[tid] = v;
  }
  __syncthreads();

  const float b1v = agg_b1[o];
  const float w2v = agg_w2[o];
  const float b2v = agg_b2[0];

  const bool bb4 = (c & 4) != 0;
  const bool bb2 = (c & 2) != 0;
  const bool bb1 = (c & 1) != 0;

  for (int hop = 0; hop < NHOP; ++hop){
    const int ibase = (b*NHOP + hop)*NMEM;

    // ---- prefetch t-rows for this group's memories (independent of softmax)
    float tv[4];
    #pragma unroll
    for (int ml = 0; ml < 4; ++ml){
      int tidx = t_i[ibase + g*4 + ml];
      tv[ml] = entity_emb[(size_t)tidx*32 + o];
    }

    // ---- C' for this hop: [i][o] ----
    #pragma unroll
    for (int k = 0; k < 4; ++k){
      int idx = tid + k*256;
      int ii = idx >> 5, oo = idx & 31;
      s_cp[idx] = s_vsM[ii*2+0]*agg_w1[oo*128 + ii]
                + s_vsM[ii*2+1]*agg_w1[oo*128 + 32 + ii];
    }

    // ---- Rh coalesced: 8 b128 loads cover the 32x32 matrix; lane holds
    //      4-col fragment of row q*4 + r_; butterfly-reduce over 8-lane
    //      cluster; lane ends with full Rh[c*4+r_].
    #pragma unroll
    for (int ml = 0; ml < 4; ++ml){
      int m    = g*4 + ml;
      int ridx = R_i[ibase + m];
      int hidx = h_i[ibase + m];
      const float* Rbase = relation_emb + (size_t)ridx*1024;
      float4 hv = *(const float4*)(entity_emb + (size_t)hidx*32 + c*4);
      float p[8];
      #pragma unroll
      for (int q = 0; q < 8; ++q){
        float4 rv = *(const float4*)(Rbase + q*128 + o*4);
        p[q] = rv.x*hv.x + rv.y*hv.y + rv.z*hv.z + rv.w*hv.w;
      }
      // stage A: partner xor 4, split q-range {0..3}|{4..7} on bit2(c)
      #pragma unroll
      for (int k = 0; k < 4; ++k){
        float send = bb4 ? p[k] : p[k+4];
        float t = __shfl_xor(send, 4);
        p[k] = (bb4 ? p[k+4] : p[k]) + t;
      }
      // stage B: partner xor 2, split on bit1(c)
      #pragma unroll
      for (int k = 0; k < 2; ++k){
        float send = bb2 ? p[k] : p[k+2];
        float t = __shfl_xor(send, 2);
        p[k] = (bb2 ? p[k+2] : p[k]) + t;
      }
      // stage C: partner xor 1, split on bit0(c)
      {
        float send = bb1 ? p[0] : p[1];
        float t = __shfl_xor(send, 1);
        p[0] = (bb1 ? p[1] : p[0]) + t;
      }
      int j = c*4 + r_;          // this lane's Rh row (bijective over 0..31)
      s_rh[(g*32 + j)*4 + ml] = p[0];
    }
    __syncthreads();

    // ---- hidden i-loop: 4 memories per group simultaneously ----
    float acc0 = 0.f, acc1 = 0.f, acc2 = 0.f, acc3 = 0.f;
    #pragma unroll 8
    for (int i = 0; i < 32; ++i){
      float2 vm  = *(const float2*)&s_vsM[i*2];            // broadcast
      float4 rh  = *(const float4*)&s_rh[(g*32 + i)*4];    // group broadcast
      float  cp  = s_cp[i*32 + o];                         // lane-varying
      float2 wcd = *(const float2*)&s_wcd[(i*32 + o)*2];   // lane-varying
      acc0 += rh.x*cp + fabsf(rh.x - vm.x)*wcd.x + fabsf(rh.x - vm.y)*wcd.y;
      acc1 += rh.y*cp + fabsf(rh.y - vm.x)*wcd.x + fabsf(rh.y - vm.y)*wcd.y;
      acc2 += rh.z*cp + fabsf(rh.z - vm.x)*wcd.x + fabsf(rh.z - vm.y)*wcd.y;
      acc3 += rh.w*cp + fabsf(rh.w - vm.x)*wcd.x + fabsf(rh.w - vm.y)*wcd.y;
    }

    // ---- per-memory score Z = w2 . tanh(hidden + b1) + b2 ----
    float accs[4] = {acc0, acc1, acc2, acc3};
    #pragma unroll
    for (int ml = 0; ml < 4; ++ml){
      float sc = tanh_f(accs[ml] + b1v) * w2v;
      #pragma unroll
      for (int s = 16; s > 0; s >>= 1) sc += __shfl_xor(sc, s);
      if (o == 0) s_Z[g*4 + ml] = sc + b2v;
    }
    __syncthreads();

    // ---- softmax over the 32 memories (lanes 0..31) ----
    if (tid < 32){
      float z  = s_Z[tid];
      float mx = z;
      #pragma unroll
      for (int s = 16; s > 0; s >>= 1) mx = fmaxf(mx, __shfl_xor(mx, s));
      float e  = __expf(z - mx);
      float sm = e;
      #pragma unroll
      for (int s = 16; s > 0; s >>= 1) sm += __shfl_xor(sm, s);
      s_g[tid] = e / sm;
    }
    __syncthreads();

    // ---- o = sum_m g[m] * t_m  (t-rows already in registers) ----
    float po = 0.f;
    #pragma unroll
    for (int ml = 0; ml < 4; ++ml)
      po += s_g[g*4 + ml] * tv[ml];
    s_opart[g*32 + o] = po;
    __syncthreads();
    if (tid < 32){
      float ov = 0.f;
      #pragma unroll
      for (int gg = 0; gg < 8; ++gg) ov += s_opart[gg*32 + tid];
      s_o[tid] = ov;
    }
    __syncthreads();

    // ---- GRU gates: gi on threads 0..95, gh on threads 128..223 ----
    if (tid < 96){
      const float* w = gru_w_ih + ((size_t)hop*96 + tid)*32;
      float a = gru_b_ih[hop*96 + tid];
      const float4* xo = (const float4*)s_o;
      #pragma unroll
      for (int jq = 0; jq < 8; ++jq){
        float4 wv = ((const float4*)w)[jq]; float4 xv = xo[jq];
        a += wv.x*xv.x + wv.y*xv.y + wv.z*xv.z + wv.w*xv.w;
      }
      s_gig[tid] = a;
    } else if (tid >= 128 && tid < 224){
      int t = tid - 128;
      const float* w = gru_w_hh + ((size_t)hop*96 + t)*32;
      float a = gru_b_hh[hop*96 + t];
      const float4* xm = (const float4*)s_M;
      #pragma unroll
      for (int jq = 0; jq < 8; ++jq){
        float4 wv = ((const float4*)w)[jq]; float4 xv = xm[jq];
        a += wv.x*xv.x + wv.y*xv.y + wv.z*xv.z + wv.w*xv.w;
      }
      s_gig[96 + t] = a;
    }
    __syncthreads();

    // ---- GRU state update (lanes 0..31) ----
    if (tid < 32){
      float ir = s_gig[tid],      iz = s_gig[32 + tid],  in_ = s_gig[64 + tid];
      float hr = s_gig[96 + tid], hz = s_gig[128 + tid], hn  = s_gig[160 + tid];
      float r  = sigmoid_f(ir + hr);
      float zz = sigmoid_f(iz + hz);
      float n  = tanh_f(in_ + r*hn);
      float Mn = (1.f - zz)*n + zz*s_M[tid];
      s_M[tid] = Mn;
      s_vsM[tid*2+1] = Mn;
    }
    __syncthreads();
  }

  // ---- epilogue: out[b] = sum_o vs_o * sigmoid(M @ ans_w.T + ans_b)_o ----
  if (tid < 32){
    const float* w = ans_w + tid*32;
    float a = ans_b[tid];
    #pragma unroll
    for (int jq = 0; jq < 8; ++jq){
      float4 wv = ((const float4*)w)[jq]; float4 mv = ((const float4*)s_M)[jq];
      a += wv.x*mv.x + wv.y*mv.y + wv.z*mv.z + wv.w*mv.w;
    }
    float mw  = sigmoid_f(a);
    float val = s_vsM[tid*2+0]*mw;
    #pragma unroll
    for (int s = 16; s > 0; s >>= 1) val += __shfl_xor(val, s);
    if (tid == 0) out[b] = val;
  }
}

extern "C" void kernel_launch(void* const* d_in, const int* in_sizes, int n_in,
                              void* d_out, int out_size, void* d_ws, size_t ws_size,
                              hipStream_t stream) {
  const int*   h_i          = (const int*)  d_in[0];
  const int*   R_i          = (const int*)  d_in[1];
  const int*   t_i          = (const int*)  d_in[2];
  const int*   v_i          = (const int*)  d_in[3];
  const float* entity_emb   = (const float*)d_in[4];
  const float* relation_emb = (const float*)d_in[5];
  const float* agg_w1       = (const float*)d_in[6];
  const float* agg_b1       = (const float*)d_in[7];
  const float* agg_w2       = (const float*)d_in[8];
  const float* agg_b2       = (const float*)d_in[9];
  const float* gru_w_ih     = (const float*)d_in[10];
  const float* gru_w_hh     = (const float*)d_in[11];
  const float* gru_b_ih     = (const float*)d_in[12];
  const float* gru_b_hh     = (const float*)d_in[13];
  const float* ans_w        = (const float*)d_in[14];
  const float* ans_b        = (const float*)d_in[15];
  float* outp = (float*)d_out;

  const int batch = in_sizes[3];   // v_i element count
  ripple_fused<<<batch, 256, 0, stream>>>(
      h_i, R_i, t_i, v_i, entity_emb, relation_emb,
      agg_w1, agg_b1, agg_w2, agg_b2,
      gru_w_ih, gru_w_hh, gru_b_ih, gru_b_hh,
      ans_w, ans_b, outp);
}